// Round 1
// baseline (274.113 us; speedup 1.0000x reference)
//
#include <hip/hip_runtime.h>
#include <math.h>

// Problem constants (AdaSpatialMLP): B=128, N=196, DIM=384, K=16, H=6, R=4
#define BB  128
#define NN  196
#define CDIM 384
#define KK  16
#define HH  6
#define DR  96    // DIM/R
#define HD  64    // DIM/H

// ---------------------------------------------------------------------------
// Stage 1: mix[b,n,k,h] = softmax_k( gelu(x@W1+b1) @ W2 + b2 )
// One block handles 8 rows of the (B*N, DIM) matrix. 192 threads = 2 j-groups
// of 96. Layout of output: [b*N+n][k*H+h] (natural), 9.6 MB in workspace.
// ---------------------------------------------------------------------------
__global__ __launch_bounds__(192) void adapter_kernel(
    const float* __restrict__ x,  const float* __restrict__ W1,
    const float* __restrict__ b1, const float* __restrict__ W2,
    const float* __restrict__ b2, float* __restrict__ mix_out)
{
    __shared__ float xs[8][CDIM];   // 12 KB
    __shared__ float hid[8][DR];    // 3 KB
    __shared__ float mv[8][DR];     // 3 KB

    const int t = threadIdx.x;
    const int row0 = blockIdx.x * 8;

    // cooperative load of 8 x-rows (coalesced float4)
    {
        const float4* xg = (const float4*)(x + (size_t)row0 * CDIM);
        float4* xs4 = (float4*)(&xs[0][0]);
        #pragma unroll
        for (int i = 0; i < 4; ++i) xs4[t + 192 * i] = xg[t + 192 * i];
    }
    __syncthreads();

    const int j  = t % DR;   // output column 0..95
    const int rh = t / DR;   // 0 or 1

    // Layer 1 + exact GELU: hid = gelu(x @ W1 + b1)
    {
        float acc[4];
        #pragma unroll
        for (int rr = 0; rr < 4; ++rr) acc[rr] = b1[j];
        for (int i = 0; i < CDIM; ++i) {
            const float w = W1[i * DR + j];           // coalesced over j
            #pragma unroll
            for (int rr = 0; rr < 4; ++rr)
                acc[rr] += xs[rh + 2 * rr][i] * w;    // LDS broadcast
        }
        #pragma unroll
        for (int rr = 0; rr < 4; ++rr) {
            const float v = acc[rr];
            hid[rh + 2 * rr][j] = 0.5f * v * (1.0f + erff(v * 0.70710678118654752f));
        }
    }
    __syncthreads();

    // Layer 2: mv = hid @ W2 + b2
    {
        float acc[4];
        #pragma unroll
        for (int rr = 0; rr < 4; ++rr) acc[rr] = b2[j];
        for (int i = 0; i < DR; ++i) {
            const float w = W2[i * DR + j];
            #pragma unroll
            for (int rr = 0; rr < 4; ++rr)
                acc[rr] += hid[rh + 2 * rr][i] * w;
        }
        #pragma unroll
        for (int rr = 0; rr < 4; ++rr) mv[rh + 2 * rr][j] = acc[rr];
    }
    __syncthreads();

    // softmax over k (stride H in mv): 48 tasks = 8 rows x 6 heads
    if (t < 48) {
        const int h = t % HH;
        const int r = t / HH;
        float mx = -1e30f;
        #pragma unroll
        for (int k = 0; k < KK; ++k) mx = fmaxf(mx, mv[r][k * HH + h]);
        float e[KK];
        float s = 0.f;
        #pragma unroll
        for (int k = 0; k < KK; ++k) { e[k] = __expf(mv[r][k * HH + h] - mx); s += e[k]; }
        const float inv = 1.0f / s;
        #pragma unroll
        for (int k = 0; k < KK; ++k) mv[r][k * HH + h] = e[k] * inv;
    }
    __syncthreads();

    // coalesced float4 writeback
    {
        const float4* mv4 = (const float4*)(&mv[0][0]);
        float4* og = (float4*)(mix_out + (size_t)row0 * DR);
        og[t] = mv4[t];   // 8*96/4 = 192 float4
    }
}

// ---------------------------------------------------------------------------
// Stage 2: out[b,m,h,c] = sum_n ( sum_k mix[b,n,k,h]*wb[k,n,m] ) * x[b,n,h*64+c]
// Grid: (7 m-tiles of 28, 128 batches). Block: 192 threads = 6 heads x 32.
// All heads share one block -> weight_bank read only B times total (315 MB L2).
// Per n-tile: stage x + mix in LDS, form A[n,m,h] tile in LDS, then
// register-tiled FMA (7m x 8c per thread).
// ---------------------------------------------------------------------------
#define TN 28
#define MT 28

__global__ __launch_bounds__(192) void mix_kernel(
    const float* __restrict__ x,  const float* __restrict__ mix,
    const float* __restrict__ wb, float* __restrict__ out)
{
    __shared__ float xs[TN][CDIM];     // 43008 B
    __shared__ float ms[TN][DR];       // 10752 B
    __shared__ float As[TN][MT][HH];   // 18816 B   (total ~71 KB -> 2 blocks/CU)

    const int t   = threadIdx.x;
    const int b   = blockIdx.y;
    const int m0  = blockIdx.x * MT;
    const int h   = t >> 5;        // 0..5
    const int tig = t & 31;
    const int mg  = tig >> 3;      // 0..3  (consecutive lanes vary cg -> coalesced stores)
    const int cg  = tig & 7;       // 0..7

    float acc[7][8];
    #pragma unroll
    for (int i = 0; i < 7; ++i)
        #pragma unroll
        for (int jj = 0; jj < 8; ++jj) acc[i][jj] = 0.f;

    for (int n0 = 0; n0 < NN; n0 += TN) {
        __syncthreads();   // previous tile fully consumed
        // stage x tile: 28 rows x 384 (coalesced float4)
        {
            const float4* xg = (const float4*)(x + ((size_t)b * NN + n0) * CDIM);
            float4* xs4 = (float4*)(&xs[0][0]);
            #pragma unroll
            for (int i = 0; i < TN * CDIM / 4 / 192; ++i)   // 14
                xs4[t + 192 * i] = xg[t + 192 * i];
        }
        // stage mix tile: 28 rows x 96 (float2)
        {
            const float2* mg2 = (const float2*)(mix + ((size_t)b * NN + n0) * DR);
            float2* ms2 = (float2*)(&ms[0][0]);
            #pragma unroll
            for (int i = 0; i < TN * DR / 2 / 192; ++i)     // 7
                ms2[t + 192 * i] = mg2[t + 192 * i];
        }
        __syncthreads();

        // form A[nl][ml][h] = sum_k ms[nl][k*6+h] * wb[k][n][m]
        for (int task = t; task < TN * MT; task += 192) {
            const int nl = task / MT;
            const int ml = task - nl * MT;
            const int n  = n0 + nl;
            const int m  = m0 + ml;
            float wv[KK];
            #pragma unroll
            for (int k = 0; k < KK; ++k)
                wv[k] = wb[((size_t)k * NN + n) * NN + m];
            #pragma unroll
            for (int hh = 0; hh < HH; ++hh) {
                float a = 0.f;
                #pragma unroll
                for (int k = 0; k < KK; ++k)
                    a += ms[nl][k * HH + hh] * wv[k];
                As[nl][ml][hh] = a;
            }
        }
        __syncthreads();

        // main FMA: acc[i][j] += A[nl][mg+4i][h] * x[nl][h*64 + cg*8 + j]
        for (int nl = 0; nl < TN; ++nl) {
            float av[7];
            #pragma unroll
            for (int i = 0; i < 7; ++i) av[i] = As[nl][mg + 4 * i][h];
            const float4 xv0 = *(const float4*)(&xs[nl][h * HD + cg * 8]);
            const float4 xv1 = *(const float4*)(&xs[nl][h * HD + cg * 8 + 4]);
            const float xv[8] = {xv0.x, xv0.y, xv0.z, xv0.w,
                                 xv1.x, xv1.y, xv1.z, xv1.w};
            #pragma unroll
            for (int i = 0; i < 7; ++i)
                #pragma unroll
                for (int jj = 0; jj < 8; ++jj)
                    acc[i][jj] += av[i] * xv[jj];
        }
    }

    // epilogue: out[b][m][h*64+c], two float4 per m-row per thread
    #pragma unroll
    for (int i = 0; i < 7; ++i) {
        const int m = m0 + mg + 4 * i;
        float* op = out + ((size_t)b * NN + m) * CDIM + h * HD + cg * 8;
        ((float4*)op)[0] = make_float4(acc[i][0], acc[i][1], acc[i][2], acc[i][3]);
        ((float4*)op)[1] = make_float4(acc[i][4], acc[i][5], acc[i][6], acc[i][7]);
    }
}

extern "C" void kernel_launch(void* const* d_in, const int* in_sizes, int n_in,
                              void* d_out, int out_size, void* d_ws, size_t ws_size,
                              hipStream_t stream) {
    (void)in_sizes; (void)n_in; (void)out_size; (void)ws_size;
    const float* x  = (const float*)d_in[0];
    const float* W1 = (const float*)d_in[1];
    const float* b1 = (const float*)d_in[2];
    const float* W2 = (const float*)d_in[3];
    const float* b2 = (const float*)d_in[4];
    const float* wb = (const float*)d_in[5];
    float* out = (float*)d_out;
    float* mixbuf = (float*)d_ws;   // B*N*96 floats = 9.63 MB

    adapter_kernel<<<(BB * NN) / 8, 192, 0, stream>>>(x, W1, b1, W2, b2, mixbuf);
    mix_kernel<<<dim3(NN / MT, BB), 192, 0, stream>>>(x, mixbuf, wb, out);
}